// Round 1
// baseline (1802.341 us; speedup 1.0000x reference)
//
#include <hip/hip_runtime.h>
#include <math.h>

#define NN 4096
#define DD 256
#define TT 32
#define GAMMA (1.0f/256.0f)
#define JBLK 32          // j-splits for the CG matvec (grid.y)
#define JCHUNK (NN/JBLK) // 128
#define ITERS 30

// ---------------------------------------------------------------- x2[i] = ||X_i||^2
__global__ void x2_kernel(const float* __restrict__ X, float* __restrict__ x2) {
    int wave = threadIdx.x >> 6;   // 4 waves per block
    int lane = threadIdx.x & 63;
    int row  = blockIdx.x * 4 + wave;
    const float* xr = X + (size_t)row * DD;
    float s = 0.f;
    #pragma unroll
    for (int d = lane; d < DD; d += 64) { float v = xr[d]; s += v * v; }
    #pragma unroll
    for (int off = 32; off; off >>= 1) s += __shfl_down(s, off);
    if (lane == 0) x2[row] = s;
}

// ---------------------------------------------------------------- K[i][j] = exp(-g*max(x2i+x2j-2*dot,0))
__global__ __launch_bounds__(256) void k_kernel(const float* __restrict__ X,
                                                const float* __restrict__ x2,
                                                float* __restrict__ K) {
    __shared__ float As[32][68];   // [k][i_local], +4 pad keeps float4 alignment, no conflicts
    __shared__ float Bs[32][68];
    const int i0 = blockIdx.x * 64, j0 = blockIdx.y * 64;
    const int tid = threadIdx.x;
    const int tx = tid & 15, ty = tid >> 4;   // 16x16 threads, 4x4 outputs each
    float acc[4][4] = {};
    for (int kc = 0; kc < DD; kc += 32) {
        #pragma unroll
        for (int r = 0; r < 8; ++r) {
            int idx = r * 256 + tid;      // 0..2047
            int ii = idx >> 5;            // 0..63
            int k  = idx & 31;
            As[k][ii] = X[(size_t)(i0 + ii) * DD + kc + k];
            Bs[k][ii] = X[(size_t)(j0 + ii) * DD + kc + k];
        }
        __syncthreads();
        #pragma unroll
        for (int k = 0; k < 32; ++k) {
            float4 a4 = *(const float4*)&As[k][ty * 4];
            float4 b4 = *(const float4*)&Bs[k][tx * 4];
            float a[4] = {a4.x, a4.y, a4.z, a4.w};
            float b[4] = {b4.x, b4.y, b4.z, b4.w};
            #pragma unroll
            for (int r = 0; r < 4; ++r)
                #pragma unroll
                for (int c = 0; c < 4; ++c) acc[r][c] += a[r] * b[c];
        }
        __syncthreads();
    }
    #pragma unroll
    for (int r = 0; r < 4; ++r) {
        int i = i0 + ty * 4 + r;
        float x2i = x2[i];
        #pragma unroll
        for (int c = 0; c < 4; ++c) {
            int j = j0 + tx * 4 + c;
            float d2 = x2i + x2[j] - 2.f * acc[r][c];
            d2 = fmaxf(d2, 0.f);
            K[(size_t)i * NN + j] = __expf(-GAMMA * d2);
        }
    }
}

// ---------------------------------------------------------------- CG init: R=P=y^T, X=0, rr0
__global__ void init_kernel(const float* __restrict__ y, float* __restrict__ R,
                            float* __restrict__ P, float* __restrict__ Xs,
                            float* __restrict__ rr0) {
    int t = blockIdx.x, tid = threadIdx.x;
    __shared__ float red[256];
    float s = 0.f;
    for (int i = tid; i < NN; i += 256) {
        float v = y[(size_t)i * TT + t];
        R[(size_t)t * NN + i] = v;
        P[(size_t)t * NN + i] = v;
        Xs[(size_t)t * NN + i] = 0.f;
        s += v * v;
    }
    red[tid] = s; __syncthreads();
    for (int o = 128; o; o >>= 1) { if (tid < o) red[tid] += red[tid + o]; __syncthreads(); }
    if (tid == 0) rr0[t] = red[0];
}

// ---------------------------------------------------------------- partial matvec: part[jb][t][i] = sum_{j in chunk jb} K[j][i]*P[t][j]
__global__ __launch_bounds__(256) void gemm_partial(const float* __restrict__ K,
                                                    const float* __restrict__ P,
                                                    float* __restrict__ part) {
    const int ib = blockIdx.x;           // 16 row-blocks of 256 i
    const int jb = blockIdx.y;           // 32 j-chunks of 128
    const int tid = threadIdx.x;
    const int i = ib * 256 + tid;
    __shared__ float pl[TT][JCHUNK];     // 32x128 = 16 KB
    #pragma unroll
    for (int r = 0; r < (TT * JCHUNK) / 256; ++r) {   // 16 iters
        int idx = r * 256 + tid;
        int t = idx >> 7, jj = idx & 127;
        pl[t][jj] = P[(size_t)t * NN + jb * JCHUNK + jj];
    }
    __syncthreads();
    float acc[TT] = {};
    const float* Kc = K + (size_t)jb * JCHUNK * NN + i;   // K[j][i], coalesced over i
    #pragma unroll 4
    for (int jj = 0; jj < JCHUNK; ++jj) {
        float k = Kc[(size_t)jj * NN];
        #pragma unroll
        for (int t = 0; t < TT; ++t) acc[t] += k * pl[t][jj];   // pl broadcast-read
    }
    float* outp = part + ((size_t)jb * TT) * NN + i;
    #pragma unroll
    for (int t = 0; t < TT; ++t) outp[(size_t)t * NN] = acc[t];
}

// ---------------------------------------------------------------- per-column CG update (one block per t)
__global__ __launch_bounds__(512) void col_update(const float* __restrict__ part,
                                                  float* __restrict__ AP,
                                                  const float* __restrict__ rr_old,
                                                  float* __restrict__ rr_new,
                                                  float* __restrict__ P,
                                                  float* __restrict__ R,
                                                  float* __restrict__ Xs) {
    const int t = blockIdx.x, tid = threadIdx.x;
    __shared__ float red[512];
    __shared__ float sc;
    // pass 1: reduce j-partials, AP = K@p + p ; pap = p.Ap
    float pap = 0.f;
    for (int i = tid; i < NN; i += 512) {
        float s = 0.f;
        #pragma unroll
        for (int b = 0; b < JBLK; ++b) s += part[((size_t)b * TT + t) * NN + i];
        float p = P[(size_t)t * NN + i];
        s += p;                                     // A = K + I
        AP[(size_t)t * NN + i] = s;
        pap += p * s;
    }
    red[tid] = pap; __syncthreads();
    for (int o = 256; o; o >>= 1) { if (tid < o) red[tid] += red[tid + o]; __syncthreads(); }
    float rro = rr_old[t];
    if (tid == 0) { float pa = red[0]; sc = (pa > 0.f) ? rro / pa : 0.f; }
    __syncthreads();
    float alpha = sc;
    // pass 2: X += a*p ; r -= a*Ap ; rr_new
    float rrl = 0.f;
    for (int i = tid; i < NN; i += 512) {
        size_t off = (size_t)t * NN + i;
        float p = P[off];
        Xs[off] += alpha * p;
        float r = R[off] - alpha * AP[off];
        R[off] = r;
        rrl += r * r;
    }
    __syncthreads();
    red[tid] = rrl; __syncthreads();
    for (int o = 256; o; o >>= 1) { if (tid < o) red[tid] += red[tid + o]; __syncthreads(); }
    if (tid == 0) {
        float rrn = red[0];
        rr_new[t] = rrn;
        sc = (rro > 0.f) ? rrn / rro : 0.f;
    }
    __syncthreads();
    float beta = sc;
    // pass 3: p = r + beta*p
    for (int i = tid; i < NN; i += 512) {
        size_t off = (size_t)t * NN + i;
        P[off] = R[off] + beta * P[off];
    }
}

// ---------------------------------------------------------------- final reduce (no +P): ypredT[t][i]
__global__ void final_reduce(const float* __restrict__ part, float* __restrict__ ypredT) {
    int t = blockIdx.x;
    int i = blockIdx.y * 512 + threadIdx.x;
    float s = 0.f;
    #pragma unroll
    for (int b = 0; b < JBLK; ++b) s += part[((size_t)b * TT + t) * NN + i];
    ypredT[(size_t)t * NN + i] = s;
}

// ---------------------------------------------------------------- [T][N] -> [N][T] coalesced
__global__ __launch_bounds__(256) void transpose_out(const float* __restrict__ ypredT,
                                                     float* __restrict__ out) {
    __shared__ float tile[TT][65];
    const int i0 = blockIdx.x * 64;
    const int tid = threadIdx.x;
    #pragma unroll
    for (int r = 0; r < 8; ++r) {
        int idx = r * 256 + tid;
        int t = idx >> 6, ii = idx & 63;
        tile[t][ii] = ypredT[(size_t)t * NN + i0 + ii];
    }
    __syncthreads();
    #pragma unroll
    for (int r = 0; r < 8; ++r) {
        int idx = r * 256 + tid;
        int ii = idx >> 5, t = idx & 31;
        out[(size_t)(i0 + ii) * TT + t] = tile[t][ii];
    }
}

extern "C" void kernel_launch(void* const* d_in, const int* in_sizes, int n_in,
                              void* d_out, int out_size, void* d_ws, size_t ws_size,
                              hipStream_t stream) {
    const float* X = (const float*)d_in[0];   // [N, D] fp32
    const float* y = (const float*)d_in[1];   // [N, T] fp32
    float* out = (float*)d_out;               // [N, T] fp32

    float* ws   = (float*)d_ws;
    float* K    = ws;                                   // N*N           (64 MB)
    float* part = K    + (size_t)NN * NN;               // JBLK*T*N      (16 MB)
    float* AP   = part + (size_t)JBLK * TT * NN;        // T*N
    float* P    = AP   + (size_t)TT * NN;               // T*N
    float* R    = P    + (size_t)TT * NN;               // T*N
    float* Xs   = R    + (size_t)TT * NN;               // T*N
    float* x2   = Xs   + (size_t)TT * NN;               // N
    float* rr   = x2   + NN;                            // 2*T (ping-pong)

    x2_kernel<<<NN / 4, 256, 0, stream>>>(X, x2);
    k_kernel<<<dim3(NN / 64, NN / 64), 256, 0, stream>>>(X, x2, K);
    init_kernel<<<TT, 256, 0, stream>>>(y, R, P, Xs, rr);

    for (int it = 0; it < ITERS; ++it) {
        gemm_partial<<<dim3(NN / 256, JBLK), 256, 0, stream>>>(K, P, part);
        col_update<<<TT, 512, 0, stream>>>(part, AP,
                                           rr + (it & 1) * TT, rr + ((it + 1) & 1) * TT,
                                           P, R, Xs);
    }

    // predict: y_pred = K @ dual  (dual = Xs, no identity term)
    gemm_partial<<<dim3(NN / 256, JBLK), 256, 0, stream>>>(K, Xs, part);
    final_reduce<<<dim3(TT, NN / 512), 512, 0, stream>>>(part, AP);  // AP reused as ypredT
    transpose_out<<<NN / 64, 256, 0, stream>>>(AP, out);
}

// Round 2
// 677.593 us; speedup vs baseline: 2.6599x; 2.6599x over previous
//
#include <hip/hip_runtime.h>
#include <math.h>

#define NN 4096
#define DD 256
#define TT 32
#define GAMMA (1.0f/256.0f)
#define ITERS 16
#define JB 32          // j-chunks in matvec
#define JCH (NN/JB)    // 128
#define KB_PAD 40      // bf16 elems per LDS row in k_build (32 data + 8 pad; 80B, 16B-aligned)

typedef __attribute__((ext_vector_type(8))) short bf16x8;
typedef __attribute__((ext_vector_type(4))) float f32x4;

static __device__ __forceinline__ unsigned short f2bf(float f) {
    unsigned int u = __float_as_uint(f);
    unsigned int r = u + 0x7FFFu + ((u >> 16) & 1u);   // RNE
    return (unsigned short)(r >> 16);
}

// ---------------------------------------------------------------- x2 + bf16 convert
__global__ __launch_bounds__(256) void x2conv(const float* __restrict__ X,
                                              float* __restrict__ x2,
                                              unsigned short* __restrict__ Xb) {
    int wid = threadIdx.x >> 6, lane = threadIdx.x & 63;
    int row = blockIdx.x * 4 + wid;
    const float* xr = X + (size_t)row * DD;
    float4 v = *(const float4*)(xr + lane * 4);
    float s = v.x * v.x + v.y * v.y + v.z * v.z + v.w * v.w;
    #pragma unroll
    for (int o = 32; o; o >>= 1) s += __shfl_down(s, o);
    if (lane == 0) x2[row] = s;
    ushort4 h;
    h.x = f2bf(v.x); h.y = f2bf(v.y); h.z = f2bf(v.z); h.w = f2bf(v.w);
    *(ushort4*)(Xb + (size_t)row * DD + lane * 4) = h;
}

// ---------------------------------------------------------------- K = exp(-g*d2) via bf16 MFMA, fp32 out
__global__ __launch_bounds__(256) void k_build(const unsigned short* __restrict__ Xb,
                                               const float* __restrict__ x2,
                                               float* __restrict__ Kout) {
    __shared__ unsigned short As[128 * KB_PAD];
    __shared__ unsigned short Bs[128 * KB_PAD];
    const int i0 = blockIdx.x * 128, j0 = blockIdx.y * 128;
    const int tid = threadIdx.x;
    const int wid = tid >> 6, lane = tid & 63;
    const int wr = wid >> 1, wc = wid & 1;
    const int l15 = lane & 15, l4 = lane >> 4;
    f32x4 acc[4][4] = {};
    for (int kc = 0; kc < DD; kc += 32) {
        __syncthreads();
        #pragma unroll
        for (int s = 0; s < 2; ++s) {
            int seg = s * 256 + tid;           // 0..511
            int row = seg >> 2, c = seg & 3;   // 128 rows x 4 chunks of 8 bf16
            uint4 d = *(const uint4*)(Xb + (size_t)(i0 + row) * DD + kc + c * 8);
            *(uint4*)(As + row * KB_PAD + c * 8) = d;
            uint4 e = *(const uint4*)(Xb + (size_t)(j0 + row) * DD + kc + c * 8);
            *(uint4*)(Bs + row * KB_PAD + c * 8) = e;
        }
        __syncthreads();
        bf16x8 af[4], bf[4];
        #pragma unroll
        for (int m = 0; m < 4; ++m)
            af[m] = *(const bf16x8*)(As + (wr * 64 + m * 16 + l15) * KB_PAD + l4 * 8);
        #pragma unroll
        for (int n = 0; n < 4; ++n)
            bf[n] = *(const bf16x8*)(Bs + (wc * 64 + n * 16 + l15) * KB_PAD + l4 * 8);
        #pragma unroll
        for (int m = 0; m < 4; ++m)
            #pragma unroll
            for (int n = 0; n < 4; ++n)
                acc[m][n] = __builtin_amdgcn_mfma_f32_16x16x32_bf16(af[m], bf[n], acc[m][n], 0, 0, 0);
    }
    #pragma unroll
    for (int m = 0; m < 4; ++m) {
        #pragma unroll
        for (int rg = 0; rg < 4; ++rg) {
            int i = i0 + wr * 64 + m * 16 + l4 * 4 + rg;
            float x2i = x2[i];
            #pragma unroll
            for (int n = 0; n < 4; ++n) {
                int j = j0 + wc * 64 + n * 16 + l15;
                float d2 = fmaxf(x2i + x2[j] - 2.f * acc[m][n][rg], 0.f);
                Kout[(size_t)i * NN + j] = __expf(-GAMMA * d2);
            }
        }
    }
}

// ---------------------------------------------------------------- CG init: r = y^T, x = 0, rr partials
__global__ __launch_bounds__(512) void cg_init(const float* __restrict__ y,
                                               float* __restrict__ r, float* __restrict__ x,
                                               float* __restrict__ rrp) {
    int t = blockIdx.x, c = blockIdx.y, tid = threadIdx.x;
    int i = c * 512 + tid;
    float v = y[(size_t)i * TT + t];
    size_t off = (size_t)t * NN + i;
    r[off] = v; x[off] = 0.f;
    float s = v * v;
    #pragma unroll
    for (int o = 32; o; o >>= 1) s += __shfl_down(s, o);
    __shared__ float red[8];
    if ((tid & 63) == 0) red[tid >> 6] = s;
    __syncthreads();
    if (tid == 0) {
        float tot = 0.f;
        #pragma unroll
        for (int u = 0; u < 8; ++u) tot += red[u];
        rrp[t * 8 + c] = tot;
    }
}

// ---------------------------------------------------------------- part[jb][t][i] = sum_{j in jb} K[j][i]*v[t][j]
__global__ __launch_bounds__(256) void matvec(const float* __restrict__ K,
                                              const float* __restrict__ v,
                                              float* __restrict__ part) {
    const int ib = blockIdx.x;   // 16
    const int jb = blockIdx.y;   // 32
    const int tid = threadIdx.x;
    __shared__ float vl[TT][JCH];
    #pragma unroll
    for (int s = 0; s < (TT * JCH) / 256; ++s) {   // 16
        int idx = s * 256 + tid;
        int t = idx >> 7, jj = idx & 127;
        vl[t][jj] = v[(size_t)t * NN + jb * JCH + jj];
    }
    __syncthreads();
    const int iq = (tid & 63) * 4;     // 4 consecutive i per thread
    const int tg = (tid >> 6) * 8;     // 8 t per thread
    float acc[8][4] = {};
    const float* Kc = K + (size_t)(jb * JCH) * NN + ib * 256 + iq;
    #pragma unroll 2
    for (int jj = 0; jj < JCH; jj += 2) {
        float4 ka = *(const float4*)(Kc + (size_t)jj * NN);
        float4 kb = *(const float4*)(Kc + (size_t)(jj + 1) * NN);
        float2 vt[8];
        #pragma unroll
        for (int u = 0; u < 8; ++u) vt[u] = *(const float2*)&vl[tg + u][jj];
        #pragma unroll
        for (int u = 0; u < 8; ++u) {
            acc[u][0] += ka.x * vt[u].x; acc[u][1] += ka.y * vt[u].x;
            acc[u][2] += ka.z * vt[u].x; acc[u][3] += ka.w * vt[u].x;
        }
        #pragma unroll
        for (int u = 0; u < 8; ++u) {
            acc[u][0] += kb.x * vt[u].y; acc[u][1] += kb.y * vt[u].y;
            acc[u][2] += kb.z * vt[u].y; acc[u][3] += kb.w * vt[u].y;
        }
    }
    float* op = part + ((size_t)jb * TT + tg) * NN + ib * 256 + iq;
    #pragma unroll
    for (int u = 0; u < 8; ++u) {
        float4 o4 = { acc[u][0], acc[u][1], acc[u][2], acc[u][3] };
        *(float4*)(op + (size_t)u * NN) = o4;
    }
}

// ---------------------------------------------------------------- w = sum_b part + r ; rw partials
// NOTE: w aliases part[31] slice — safe: each thread reads all 32 partials before its write.
__global__ __launch_bounds__(512) void bred(const float* part, const float* __restrict__ r,
                                            float* w, float* __restrict__ rwp) {
    int t = blockIdx.x, c = blockIdx.y, tid = threadIdx.x;
    int i = c * 512 + tid;
    float s = 0.f;
    #pragma unroll
    for (int b = 0; b < JB; ++b) s += part[((size_t)b * TT + t) * NN + i];
    float rv = r[(size_t)t * NN + i];
    s += rv;                                   // A = K + I
    w[(size_t)t * NN + i] = s;
    float v = rv * s;
    #pragma unroll
    for (int o = 32; o; o >>= 1) v += __shfl_down(v, o);
    __shared__ float red[8];
    if ((tid & 63) == 0) red[tid >> 6] = v;
    __syncthreads();
    if (tid == 0) {
        float tot = 0.f;
        #pragma unroll
        for (int u = 0; u < 8; ++u) tot += red[u];
        rwp[t * 8 + c] = tot;
    }
}

// ---------------------------------------------------------------- Chronopoulos-Gear update
__global__ __launch_bounds__(512) void cupd(const float* __restrict__ w, float* __restrict__ r,
                                            float* __restrict__ p, float* __restrict__ s_,
                                            float* __restrict__ x,
                                            const float* __restrict__ rrp_in,
                                            float* __restrict__ rrp_out,
                                            const float* __restrict__ rwp,
                                            const float* __restrict__ scal_in,
                                            float* __restrict__ scal_out, int first) {
    int t = blockIdx.x, c = blockIdx.y, tid = threadIdx.x;
    float rr = 0.f, rw = 0.f;
    #pragma unroll
    for (int u = 0; u < 8; ++u) { rr += rrp_in[t * 8 + u]; rw += rwp[t * 8 + u]; }
    float alpha, beta;
    if (first) {
        beta = 0.f;
        alpha = rr / rw;
    } else {
        float ap = scal_in[t], rrprev = scal_in[TT + t];
        beta = rr / rrprev;
        alpha = rr / (rw - (beta / ap) * rr);
    }
    size_t off = (size_t)t * NN + c * 512 + tid;
    float rv = r[off], wv = w[off];
    float pn = first ? rv : fmaf(beta, p[off], rv);
    float sn = first ? wv : fmaf(beta, s_[off], wv);
    p[off] = pn; s_[off] = sn;
    x[off] += alpha * pn;
    float rn = rv - alpha * sn;
    r[off] = rn;
    float v = rn * rn;
    #pragma unroll
    for (int o = 32; o; o >>= 1) v += __shfl_down(v, o);
    __shared__ float red[8];
    if ((tid & 63) == 0) red[tid >> 6] = v;
    __syncthreads();
    if (tid == 0) {
        float tot = 0.f;
        #pragma unroll
        for (int u = 0; u < 8; ++u) tot += red[u];
        rrp_out[t * 8 + c] = tot;
        if (c == 0) { scal_out[t] = alpha; scal_out[TT + t] = rr; }
    }
}

// ---------------------------------------------------------------- y_pred[i][t] = sum_b part (transposed write)
__global__ __launch_bounds__(256) void predict_out(const float* __restrict__ part,
                                                   float* __restrict__ out) {
    __shared__ float st[TT][65];
    const int i0 = blockIdx.x * 64;
    const int tid = threadIdx.x;
    #pragma unroll
    for (int ph = 0; ph < 8; ++ph) {
        int idx = ph * 256 + tid;
        int il = idx & 63, t = idx >> 6;
        float s = 0.f;
        #pragma unroll
        for (int b = 0; b < JB; ++b) s += part[((size_t)b * TT + t) * NN + i0 + il];
        st[t][il] = s;
    }
    __syncthreads();
    #pragma unroll
    for (int ph = 0; ph < 8; ++ph) {
        int idx = ph * 256 + tid;
        int t = idx & 31, il = idx >> 5;
        out[(size_t)(i0 + il) * TT + t] = st[t][il];
    }
}

extern "C" void kernel_launch(void* const* d_in, const int* in_sizes, int n_in,
                              void* d_out, int out_size, void* d_ws, size_t ws_size,
                              hipStream_t stream) {
    const float* X = (const float*)d_in[0];   // [N, D]
    const float* y = (const float*)d_in[1];   // [N, T]
    float* out = (float*)d_out;               // [N, T]

    float* ws = (float*)d_ws;
    float* K    = ws;                                   // 16M floats (64 MB)
    float* part = K + (size_t)NN * NN;                  // 32*32*4096 = 4M floats (16 MB)
    // Xb and x2 overlay part (dead until first matvec)
    unsigned short* Xb = (unsigned short*)part;         // N*D ushorts (2 MB)
    float* x2  = part + 600000;                         // N floats, past Xb (524288 ushorts)
    float* w   = part + (size_t)(JB - 1) * TT * NN;     // aliases part[31] slice
    float* r   = part + (size_t)JB * TT * NN;           // T*N
    float* p   = r   + (size_t)TT * NN;
    float* s_  = p   + (size_t)TT * NN;
    float* x   = s_  + (size_t)TT * NN;
    float* rrp = x   + (size_t)TT * NN;                 // 2 slots x 256
    float* rwp = rrp + 512;                             // 256
    float* scal= rwp + 256;                             // 2 slots x 64

    x2conv<<<NN / 4, 256, 0, stream>>>(X, x2, Xb);
    k_build<<<dim3(NN / 128, NN / 128), 256, 0, stream>>>(Xb, x2, K);
    cg_init<<<dim3(TT, 8), 512, 0, stream>>>(y, r, x, rrp);

    for (int j = 0; j < ITERS; ++j) {
        matvec<<<dim3(NN / 256, JB), 256, 0, stream>>>(K, r, part);
        bred<<<dim3(TT, 8), 512, 0, stream>>>(part, r, w, rwp);
        cupd<<<dim3(TT, 8), 512, 0, stream>>>(w, r, p, s_, x,
                                              rrp + (j & 1) * 256, rrp + ((j + 1) & 1) * 256,
                                              rwp,
                                              scal + (j & 1) * 64, scal + ((j + 1) & 1) * 64,
                                              j == 0 ? 1 : 0);
    }

    // predict: y_pred = K @ x (no identity term)
    matvec<<<dim3(NN / 256, JB), 256, 0, stream>>>(K, x, part);
    predict_out<<<NN / 64, 256, 0, stream>>>(part, out);
}

// Round 3
// 497.323 us; speedup vs baseline: 3.6241x; 1.3625x over previous
//
#include <hip/hip_runtime.h>
#include <math.h>

#define NN 4096
#define DD 256
#define TT 32
#define GAMMA (1.0f/256.0f)
#define ITERS 14
#define JBP 8            // j-chunks in MFMA matvec
#define JCHP (NN/JBP)    // 512
#define KB_PAD 40        // bf16 elems per LDS row in k_build

typedef __attribute__((ext_vector_type(8))) short bf16x8;
typedef __attribute__((ext_vector_type(4))) float f32x4;

static __device__ __forceinline__ unsigned short f2bf(float f) {
    unsigned int u = __float_as_uint(f);
    unsigned int r = u + 0x7FFFu + ((u >> 16) & 1u);   // RNE
    return (unsigned short)(r >> 16);
}
static __device__ __forceinline__ float bf2f(unsigned short h) {
    return __uint_as_float((unsigned int)h << 16);
}
static __device__ __forceinline__ unsigned int pack_hilo(float v) {
    unsigned short h = f2bf(v);
    unsigned short l = f2bf(v - bf2f(h));
    return (unsigned int)h | ((unsigned int)l << 16);
}
static __device__ __forceinline__ bf16x8 mk_hi(const uint4& q0, const uint4& q1) {
    union { unsigned int u[4]; bf16x8 b; } r;
    r.u[0] = (q0.x & 0xffffu) | (q0.y << 16);
    r.u[1] = (q0.z & 0xffffu) | (q0.w << 16);
    r.u[2] = (q1.x & 0xffffu) | (q1.y << 16);
    r.u[3] = (q1.z & 0xffffu) | (q1.w << 16);
    return r.b;
}
static __device__ __forceinline__ bf16x8 mk_lo(const uint4& q0, const uint4& q1) {
    union { unsigned int u[4]; bf16x8 b; } r;
    r.u[0] = (q0.x >> 16) | (q0.y & 0xffff0000u);
    r.u[1] = (q0.z >> 16) | (q0.w & 0xffff0000u);
    r.u[2] = (q1.x >> 16) | (q1.y & 0xffff0000u);
    r.u[3] = (q1.z >> 16) | (q1.w & 0xffff0000u);
    return r.b;
}

// ---------------------------------------------------------------- x2 + bf16 convert of X
__global__ __launch_bounds__(256) void x2conv(const float* __restrict__ X,
                                              float* __restrict__ x2,
                                              unsigned short* __restrict__ Xb) {
    int wid = threadIdx.x >> 6, lane = threadIdx.x & 63;
    int row = blockIdx.x * 4 + wid;
    const float* xr = X + (size_t)row * DD;
    float4 v = *(const float4*)(xr + lane * 4);
    float s = v.x * v.x + v.y * v.y + v.z * v.z + v.w * v.w;
    #pragma unroll
    for (int o = 32; o; o >>= 1) s += __shfl_down(s, o);
    if (lane == 0) x2[row] = s;
    ushort4 h;
    h.x = f2bf(v.x); h.y = f2bf(v.y); h.z = f2bf(v.z); h.w = f2bf(v.w);
    *(ushort4*)(Xb + (size_t)row * DD + lane * 4) = h;
}

// ---------------------------------------------------------------- K = exp(-g*d2), stored packed bf16 hi/lo
__global__ __launch_bounds__(256) void k_build(const unsigned short* __restrict__ Xb,
                                               const float* __restrict__ x2,
                                               unsigned int* __restrict__ Kp) {
    __shared__ unsigned short As[128 * KB_PAD];
    __shared__ unsigned short Bs[128 * KB_PAD];
    const int i0 = blockIdx.x * 128, j0 = blockIdx.y * 128;
    const int tid = threadIdx.x;
    const int wid = tid >> 6, lane = tid & 63;
    const int wr = wid >> 1, wc = wid & 1;
    const int l15 = lane & 15, l4 = lane >> 4;
    f32x4 acc[4][4] = {};
    for (int kc = 0; kc < DD; kc += 32) {
        __syncthreads();
        #pragma unroll
        for (int s = 0; s < 2; ++s) {
            int seg = s * 256 + tid;
            int row = seg >> 2, c = seg & 3;
            uint4 d = *(const uint4*)(Xb + (size_t)(i0 + row) * DD + kc + c * 8);
            *(uint4*)(As + row * KB_PAD + c * 8) = d;
            uint4 e = *(const uint4*)(Xb + (size_t)(j0 + row) * DD + kc + c * 8);
            *(uint4*)(Bs + row * KB_PAD + c * 8) = e;
        }
        __syncthreads();
        bf16x8 af[4], bf[4];
        #pragma unroll
        for (int m = 0; m < 4; ++m)
            af[m] = *(const bf16x8*)(As + (wr * 64 + m * 16 + l15) * KB_PAD + l4 * 8);
        #pragma unroll
        for (int n = 0; n < 4; ++n)
            bf[n] = *(const bf16x8*)(Bs + (wc * 64 + n * 16 + l15) * KB_PAD + l4 * 8);
        #pragma unroll
        for (int m = 0; m < 4; ++m)
            #pragma unroll
            for (int n = 0; n < 4; ++n)
                acc[m][n] = __builtin_amdgcn_mfma_f32_16x16x32_bf16(af[m], bf[n], acc[m][n], 0, 0, 0);
    }
    #pragma unroll
    for (int m = 0; m < 4; ++m) {
        #pragma unroll
        for (int rg = 0; rg < 4; ++rg) {
            int i = i0 + wr * 64 + m * 16 + l4 * 4 + rg;
            float x2i = x2[i];
            #pragma unroll
            for (int n = 0; n < 4; ++n) {
                int j = j0 + wc * 64 + n * 16 + l15;
                float d2 = fmaxf(x2i + x2[j] - 2.f * acc[m][n][rg], 0.f);
                Kp[(size_t)i * NN + j] = pack_hilo(__expf(-GAMMA * d2));
            }
        }
    }
}

// ---------------------------------------------------------------- CG init: r = y^T (fp32 + bf16 hi/lo), x = 0
__global__ __launch_bounds__(512) void cg_init(const float* __restrict__ y,
                                               float* __restrict__ r, float* __restrict__ x,
                                               unsigned short* __restrict__ rhi,
                                               unsigned short* __restrict__ rlo,
                                               float* __restrict__ rrp) {
    int t = blockIdx.x, c = blockIdx.y, tid = threadIdx.x;
    int i = c * 512 + tid;
    float v = y[(size_t)i * TT + t];
    size_t off = (size_t)t * NN + i;
    r[off] = v; x[off] = 0.f;
    unsigned short h = f2bf(v);
    rhi[off] = h; rlo[off] = f2bf(v - bf2f(h));
    float s = v * v;
    #pragma unroll
    for (int o = 32; o; o >>= 1) s += __shfl_down(s, o);
    __shared__ float red[8];
    if ((tid & 63) == 0) red[tid >> 6] = s;
    __syncthreads();
    if (tid == 0) {
        float tot = 0.f;
        #pragma unroll
        for (int u = 0; u < 8; ++u) tot += red[u];
        rrp[t * 8 + c] = tot;
    }
}

// ---------------------------------------------------------------- MFMA matvec: part[jb][t][i] = sum_{j in jb} K[i][j]*v[t][j]
// K symmetric so K[i][j] rows feed the A operand directly.
__global__ __launch_bounds__(256) void matvec_mfma(const unsigned int* __restrict__ Kp,
                                                   const unsigned short* __restrict__ vhi,
                                                   const unsigned short* __restrict__ vlo,
                                                   float* __restrict__ part) {
    __shared__ float tl[4][32][17];
    const int ib = blockIdx.x;   // 64 blocks of 64 i
    const int jb = blockIdx.y;   // 8 chunks of 512 j
    const int wid = threadIdx.x >> 6, lane = threadIdx.x & 63;
    const int i0 = ib * 64 + wid * 16;
    const int l15 = lane & 15, l4 = lane >> 4;
    const unsigned int*  Ap = Kp  + (size_t)(i0 + l15) * NN + jb * JCHP + l4 * 8;
    const unsigned short* Bh = vhi + (size_t)l15 * NN + jb * JCHP + l4 * 8;
    const unsigned short* Bl = vlo + (size_t)l15 * NN + jb * JCHP + l4 * 8;
    f32x4 acc0 = {}, acc1 = {};
    #pragma unroll 2
    for (int jc = 0; jc < JCHP; jc += 32) {
        uint4 q0 = *(const uint4*)(Ap + jc);
        uint4 q1 = *(const uint4*)(Ap + jc + 4);
        bf16x8 ah = mk_hi(q0, q1);
        bf16x8 al = mk_lo(q0, q1);
        bf16x8 bh0 = *(const bf16x8*)(Bh + jc);
        bf16x8 bh1 = *(const bf16x8*)(Bh + 16 * NN + jc);
        bf16x8 bl0 = *(const bf16x8*)(Bl + jc);
        bf16x8 bl1 = *(const bf16x8*)(Bl + 16 * NN + jc);
        acc0 = __builtin_amdgcn_mfma_f32_16x16x32_bf16(ah, bh0, acc0, 0, 0, 0);
        acc1 = __builtin_amdgcn_mfma_f32_16x16x32_bf16(ah, bh1, acc1, 0, 0, 0);
        acc0 = __builtin_amdgcn_mfma_f32_16x16x32_bf16(al, bh0, acc0, 0, 0, 0);
        acc1 = __builtin_amdgcn_mfma_f32_16x16x32_bf16(al, bh1, acc1, 0, 0, 0);
        acc0 = __builtin_amdgcn_mfma_f32_16x16x32_bf16(ah, bl0, acc0, 0, 0, 0);
        acc1 = __builtin_amdgcn_mfma_f32_16x16x32_bf16(ah, bl1, acc1, 0, 0, 0);
    }
    // C layout: row = l4*4+rg (i-local), col = l15 (t). Transpose via LDS for coalesced store.
    #pragma unroll
    for (int rg = 0; rg < 4; ++rg) {
        tl[wid][l15][l4 * 4 + rg] = acc0[rg];
        tl[wid][16 + l15][l4 * 4 + rg] = acc1[rg];
    }
    __syncthreads();
    #pragma unroll
    for (int q = 0; q < 8; ++q) {
        int idx = q * 64 + lane;
        int t = idx >> 4, il = idx & 15;
        part[((size_t)jb * TT + t) * NN + i0 + il] = tl[wid][t][il];
    }
}

// ---------------------------------------------------------------- w = sum_b part + r ; rw partials
// NOTE: w aliases part[JBP-1] slice — safe: each thread reads all partials before its write.
__global__ __launch_bounds__(512) void bred(const float* part, const float* __restrict__ r,
                                            float* w, float* __restrict__ rwp) {
    int t = blockIdx.x, c = blockIdx.y, tid = threadIdx.x;
    int i = c * 512 + tid;
    float s = 0.f;
    #pragma unroll
    for (int b = 0; b < JBP; ++b) s += part[((size_t)b * TT + t) * NN + i];
    float rv = r[(size_t)t * NN + i];
    s += rv;                                   // A = K + I
    w[(size_t)t * NN + i] = s;
    float v = rv * s;
    #pragma unroll
    for (int o = 32; o; o >>= 1) v += __shfl_down(v, o);
    __shared__ float red[8];
    if ((tid & 63) == 0) red[tid >> 6] = v;
    __syncthreads();
    if (tid == 0) {
        float tot = 0.f;
        #pragma unroll
        for (int u = 0; u < 8; ++u) tot += red[u];
        rwp[t * 8 + c] = tot;
    }
}

// ---------------------------------------------------------------- Chronopoulos-Gear update (+ bf16 r out)
__global__ __launch_bounds__(512) void cupd(const float* __restrict__ w, float* __restrict__ r,
                                            float* __restrict__ p, float* __restrict__ s_,
                                            float* __restrict__ x,
                                            unsigned short* __restrict__ rhi,
                                            unsigned short* __restrict__ rlo,
                                            const float* __restrict__ rrp_in,
                                            float* __restrict__ rrp_out,
                                            const float* __restrict__ rwp,
                                            const float* __restrict__ scal_in,
                                            float* __restrict__ scal_out, int first) {
    int t = blockIdx.x, c = blockIdx.y, tid = threadIdx.x;
    float rr = 0.f, rw = 0.f;
    #pragma unroll
    for (int u = 0; u < 8; ++u) { rr += rrp_in[t * 8 + u]; rw += rwp[t * 8 + u]; }
    float alpha, beta;
    if (first) {
        beta = 0.f;
        alpha = rr / rw;
    } else {
        float ap = scal_in[t], rrprev = scal_in[TT + t];
        beta = rr / rrprev;
        alpha = rr / (rw - (beta / ap) * rr);
    }
    size_t off = (size_t)t * NN + c * 512 + tid;
    float rv = r[off], wv = w[off];
    float pn = first ? rv : fmaf(beta, p[off], rv);
    float sn = first ? wv : fmaf(beta, s_[off], wv);
    p[off] = pn; s_[off] = sn;
    x[off] += alpha * pn;
    float rn = rv - alpha * sn;
    r[off] = rn;
    unsigned short h = f2bf(rn);
    rhi[off] = h; rlo[off] = f2bf(rn - bf2f(h));
    float v = rn * rn;
    #pragma unroll
    for (int o = 32; o; o >>= 1) v += __shfl_down(v, o);
    __shared__ float red[8];
    if ((tid & 63) == 0) red[tid >> 6] = v;
    __syncthreads();
    if (tid == 0) {
        float tot = 0.f;
        #pragma unroll
        for (int u = 0; u < 8; ++u) tot += red[u];
        rrp_out[t * 8 + c] = tot;
        if (c == 0) { scal_out[t] = alpha; scal_out[TT + t] = rr; }
    }
}

// ---------------------------------------------------------------- fp32 [T][N] -> bf16 hi/lo
__global__ __launch_bounds__(512) void vec2bf(const float* __restrict__ v,
                                              unsigned short* __restrict__ hi,
                                              unsigned short* __restrict__ lo) {
    int t = blockIdx.x, c = blockIdx.y, tid = threadIdx.x;
    size_t off = (size_t)t * NN + c * 512 + tid;
    float val = v[off];
    unsigned short h = f2bf(val);
    hi[off] = h; lo[off] = f2bf(val - bf2f(h));
}

// ---------------------------------------------------------------- y_pred[i][t] = sum_b part (transposed write)
__global__ __launch_bounds__(256) void predict_out(const float* __restrict__ part,
                                                   float* __restrict__ out) {
    __shared__ float st[TT][65];
    const int i0 = blockIdx.x * 64;
    const int tid = threadIdx.x;
    #pragma unroll
    for (int ph = 0; ph < 8; ++ph) {
        int idx = ph * 256 + tid;
        int il = idx & 63, t = idx >> 6;
        float s = 0.f;
        #pragma unroll
        for (int b = 0; b < JBP; ++b) s += part[((size_t)b * TT + t) * NN + i0 + il];
        st[t][il] = s;
    }
    __syncthreads();
    #pragma unroll
    for (int ph = 0; ph < 8; ++ph) {
        int idx = ph * 256 + tid;
        int t = idx & 31, il = idx >> 5;
        out[(size_t)(i0 + il) * TT + t] = st[t][il];
    }
}

extern "C" void kernel_launch(void* const* d_in, const int* in_sizes, int n_in,
                              void* d_out, int out_size, void* d_ws, size_t ws_size,
                              hipStream_t stream) {
    const float* X = (const float*)d_in[0];   // [N, D]
    const float* y = (const float*)d_in[1];   // [N, T]
    float* out = (float*)d_out;               // [N, T]

    unsigned int* Kp = (unsigned int*)d_ws;                       // N*N uints (64 MB)
    float* part = (float*)(Kp + (size_t)NN * NN);                 // JBP*T*N (4 MB)
    float* w    = part + (size_t)(JBP - 1) * TT * NN;             // aliases part[JBP-1]
    float* r    = part + (size_t)JBP * TT * NN;                   // T*N
    float* p    = r  + (size_t)TT * NN;
    float* s_   = p  + (size_t)TT * NN;
    float* x    = s_ + (size_t)TT * NN;
    unsigned short* rhi = (unsigned short*)(x + (size_t)TT * NN); // T*N bf16
    unsigned short* rlo = rhi + (size_t)TT * NN;
    unsigned short* xhi = rlo + (size_t)TT * NN;
    unsigned short* xlo = xhi + (size_t)TT * NN;
    float* rrp  = (float*)(xlo + (size_t)TT * NN);                // 2 x 256
    float* rwp  = rrp + 512;                                      // 256
    float* scal = rwp + 256;                                      // 2 x 64
    unsigned short* Xb = (unsigned short*)(scal + 128);           // N*D bf16 (2 MB)
    float* x2v  = (float*)(Xb + (size_t)NN * DD);                 // N

    x2conv<<<NN / 4, 256, 0, stream>>>(X, x2v, Xb);
    k_build<<<dim3(NN / 128, NN / 128), 256, 0, stream>>>(Xb, x2v, Kp);
    cg_init<<<dim3(TT, 8), 512, 0, stream>>>(y, r, x, rhi, rlo, rrp);

    for (int j = 0; j < ITERS; ++j) {
        matvec_mfma<<<dim3(NN / 64, JBP), 256, 0, stream>>>(Kp, rhi, rlo, part);
        bred<<<dim3(TT, 8), 512, 0, stream>>>(part, r, w, rwp);
        cupd<<<dim3(TT, 8), 512, 0, stream>>>(w, r, p, s_, x, rhi, rlo,
                                              rrp + (j & 1) * 256, rrp + ((j + 1) & 1) * 256,
                                              rwp,
                                              scal + (j & 1) * 64, scal + ((j + 1) & 1) * 64,
                                              j == 0 ? 1 : 0);
    }

    // predict: y_pred = K @ x (no identity term)
    vec2bf<<<dim3(TT, 8), 512, 0, stream>>>(x, xhi, xlo);
    matvec_mfma<<<dim3(NN / 64, JBP), 256, 0, stream>>>(Kp, xhi, xlo, part);
    predict_out<<<NN / 64, 256, 0, stream>>>(part, out);
}

// Round 4
// 412.634 us; speedup vs baseline: 4.3679x; 1.2052x over previous
//
#include <hip/hip_runtime.h>
#include <math.h>

#define NN 4096
#define DD 256
#define TT 32
#define GAMMA (1.0f/256.0f)
#define ITERS 10
#define KB_PAD 40        // bf16 elems per LDS row in k_build

typedef __attribute__((ext_vector_type(8))) short bf16x8;
typedef __attribute__((ext_vector_type(4))) float f32x4;

static __device__ __forceinline__ unsigned short f2bf(float f) {
    unsigned int u = __float_as_uint(f);
    unsigned int r = u + 0x7FFFu + ((u >> 16) & 1u);   // RNE
    return (unsigned short)(r >> 16);
}
static __device__ __forceinline__ float bf2f(unsigned short h) {
    return __uint_as_float((unsigned int)h << 16);
}
static __device__ __forceinline__ unsigned int pack_hilo(float v) {
    unsigned short h = f2bf(v);
    unsigned short l = f2bf(v - bf2f(h));
    return (unsigned int)h | ((unsigned int)l << 16);
}
static __device__ __forceinline__ bf16x8 mk_hi(const uint4& q0, const uint4& q1) {
    union { unsigned int u[4]; bf16x8 b; } r;
    r.u[0] = (q0.x & 0xffffu) | (q0.y << 16);
    r.u[1] = (q0.z & 0xffffu) | (q0.w << 16);
    r.u[2] = (q1.x & 0xffffu) | (q1.y << 16);
    r.u[3] = (q1.z & 0xffffu) | (q1.w << 16);
    return r.b;
}
static __device__ __forceinline__ bf16x8 mk_lo(const uint4& q0, const uint4& q1) {
    union { unsigned int u[4]; bf16x8 b; } r;
    r.u[0] = (q0.x >> 16) | (q0.y & 0xffff0000u);
    r.u[1] = (q0.z >> 16) | (q0.w & 0xffff0000u);
    r.u[2] = (q1.x >> 16) | (q1.y & 0xffff0000u);
    r.u[3] = (q1.z >> 16) | (q1.w & 0xffff0000u);
    return r.b;
}

// ---------------------------------------------------------------- x2 + bf16 convert of X
__global__ __launch_bounds__(256) void x2conv(const float* __restrict__ X,
                                              float* __restrict__ x2,
                                              unsigned short* __restrict__ Xb) {
    int wid = threadIdx.x >> 6, lane = threadIdx.x & 63;
    int row = blockIdx.x * 4 + wid;
    const float* xr = X + (size_t)row * DD;
    float4 v = *(const float4*)(xr + lane * 4);
    float s = v.x * v.x + v.y * v.y + v.z * v.z + v.w * v.w;
    #pragma unroll
    for (int o = 32; o; o >>= 1) s += __shfl_down(s, o);
    if (lane == 0) x2[row] = s;
    ushort4 h;
    h.x = f2bf(v.x); h.y = f2bf(v.y); h.z = f2bf(v.z); h.w = f2bf(v.w);
    *(ushort4*)(Xb + (size_t)row * DD + lane * 4) = h;
}

// ---------------------------------------------------------------- K = exp(-g*d2), stored packed bf16 hi/lo
__global__ __launch_bounds__(256) void k_build(const unsigned short* __restrict__ Xb,
                                               const float* __restrict__ x2,
                                               unsigned int* __restrict__ Kp) {
    __shared__ unsigned short As[128 * KB_PAD];
    __shared__ unsigned short Bs[128 * KB_PAD];
    const int i0 = blockIdx.x * 128, j0 = blockIdx.y * 128;
    const int tid = threadIdx.x;
    const int wid = tid >> 6, lane = tid & 63;
    const int wr = wid >> 1, wc = wid & 1;
    const int l15 = lane & 15, l4 = lane >> 4;
    f32x4 acc[4][4] = {};
    for (int kc = 0; kc < DD; kc += 32) {
        __syncthreads();
        #pragma unroll
        for (int s = 0; s < 2; ++s) {
            int seg = s * 256 + tid;
            int row = seg >> 2, c = seg & 3;
            uint4 d = *(const uint4*)(Xb + (size_t)(i0 + row) * DD + kc + c * 8);
            *(uint4*)(As + row * KB_PAD + c * 8) = d;
            uint4 e = *(const uint4*)(Xb + (size_t)(j0 + row) * DD + kc + c * 8);
            *(uint4*)(Bs + row * KB_PAD + c * 8) = e;
        }
        __syncthreads();
        bf16x8 af[4], bf[4];
        #pragma unroll
        for (int m = 0; m < 4; ++m)
            af[m] = *(const bf16x8*)(As + (wr * 64 + m * 16 + l15) * KB_PAD + l4 * 8);
        #pragma unroll
        for (int n = 0; n < 4; ++n)
            bf[n] = *(const bf16x8*)(Bs + (wc * 64 + n * 16 + l15) * KB_PAD + l4 * 8);
        #pragma unroll
        for (int m = 0; m < 4; ++m)
            #pragma unroll
            for (int n = 0; n < 4; ++n)
                acc[m][n] = __builtin_amdgcn_mfma_f32_16x16x32_bf16(af[m], bf[n], acc[m][n], 0, 0, 0);
    }
    #pragma unroll
    for (int m = 0; m < 4; ++m) {
        #pragma unroll
        for (int rg = 0; rg < 4; ++rg) {
            int i = i0 + wr * 64 + m * 16 + l4 * 4 + rg;
            float x2i = x2[i];
            #pragma unroll
            for (int n = 0; n < 4; ++n) {
                int j = j0 + wc * 64 + n * 16 + l15;
                float d2 = fmaxf(x2i + x2[j] - 2.f * acc[m][n][rg], 0.f);
                Kp[(size_t)i * NN + j] = pack_hilo(__expf(-GAMMA * d2));
            }
        }
    }
}

// ---------------------------------------------------------------- CG init: r = y^T (fp32 + bf16 hi/lo), x = 0
__global__ __launch_bounds__(512) void cg_init(const float* __restrict__ y,
                                               float* __restrict__ r, float* __restrict__ x,
                                               unsigned short* __restrict__ rhi,
                                               unsigned short* __restrict__ rlo,
                                               float* __restrict__ rrp) {
    int t = blockIdx.x, c = blockIdx.y, tid = threadIdx.x;
    int i = c * 512 + tid;
    float v = y[(size_t)i * TT + t];
    size_t off = (size_t)t * NN + i;
    r[off] = v; x[off] = 0.f;
    unsigned short h = f2bf(v);
    rhi[off] = h; rlo[off] = f2bf(v - bf2f(h));
    float s = v * v;
    #pragma unroll
    for (int o = 32; o; o >>= 1) s += __shfl_down(s, o);
    __shared__ float red[8];
    if ((tid & 63) == 0) red[tid >> 6] = s;
    __syncthreads();
    if (tid == 0) {
        float tot = 0.f;
        #pragma unroll
        for (int u = 0; u < 8; ++u) tot += red[u];
        rrp[t * 8 + c] = tot;
    }
}

// ---------------------------------------------------------------- fused matvec: block = 16 i-rows, 8 waves x 512-j chunks
// STORE_OUT=0: w[t][i] = (K v)[t][i] + r[t][i]; rwp[t][blk] = sum_i r*w
// STORE_OUT=1: out[i][t] = (K v)[t][i]          (predict path)
template<int STORE_OUT>
__global__ __launch_bounds__(512) void matvec_fused(const unsigned int* __restrict__ Kp,
                                                    const unsigned short* __restrict__ vhi,
                                                    const unsigned short* __restrict__ vlo,
                                                    const float* __restrict__ r,
                                                    float* __restrict__ w,
                                                    float* __restrict__ rwp,
                                                    float* __restrict__ out) {
    __shared__ float tl[8][32][17];
    const int ib = blockIdx.x;                    // 256 blocks
    const int tid = threadIdx.x;
    const int wid = tid >> 6, lane = tid & 63;
    const int i0 = ib * 16;
    const int l15 = lane & 15, l4 = lane >> 4;
    const int jbase = wid * 512;
    const unsigned int*  Ap = Kp  + (size_t)(i0 + l15) * NN + jbase + l4 * 8;
    const unsigned short* Bh = vhi + (size_t)l15 * NN + jbase + l4 * 8;
    const unsigned short* Bl = vlo + (size_t)l15 * NN + jbase + l4 * 8;
    f32x4 acc0 = {}, acc1 = {};
    #pragma unroll 4
    for (int jc = 0; jc < 512; jc += 32) {
        uint4 q0 = *(const uint4*)(Ap + jc);
        uint4 q1 = *(const uint4*)(Ap + jc + 4);
        bf16x8 ah = mk_hi(q0, q1);
        bf16x8 al = mk_lo(q0, q1);
        bf16x8 bh0 = *(const bf16x8*)(Bh + jc);
        bf16x8 bh1 = *(const bf16x8*)(Bh + (size_t)16 * NN + jc);
        bf16x8 bl0 = *(const bf16x8*)(Bl + jc);
        bf16x8 bl1 = *(const bf16x8*)(Bl + (size_t)16 * NN + jc);
        acc0 = __builtin_amdgcn_mfma_f32_16x16x32_bf16(ah, bh0, acc0, 0, 0, 0);
        acc1 = __builtin_amdgcn_mfma_f32_16x16x32_bf16(ah, bh1, acc1, 0, 0, 0);
        acc0 = __builtin_amdgcn_mfma_f32_16x16x32_bf16(al, bh0, acc0, 0, 0, 0);
        acc1 = __builtin_amdgcn_mfma_f32_16x16x32_bf16(al, bh1, acc1, 0, 0, 0);
        acc0 = __builtin_amdgcn_mfma_f32_16x16x32_bf16(ah, bl0, acc0, 0, 0, 0);
        acc1 = __builtin_amdgcn_mfma_f32_16x16x32_bf16(ah, bl1, acc1, 0, 0, 0);
    }
    // C layout: row (i-local) = l4*4+rg, col (t) = l15
    #pragma unroll
    for (int rg = 0; rg < 4; ++rg) {
        tl[wid][l15][l4 * 4 + rg]      = acc0[rg];
        tl[wid][16 + l15][l4 * 4 + rg] = acc1[rg];
    }
    __syncthreads();
    if (STORE_OUT) {
        const int t = tid & 31, il = tid >> 5;    // consecutive tid -> consecutive t
        float s = 0.f;
        #pragma unroll
        for (int u = 0; u < 8; ++u) s += tl[u][t][il];
        out[(size_t)(i0 + il) * TT + t] = s;
    } else {
        const int t = tid >> 4, il = tid & 15;    // consecutive tid -> consecutive i
        float s = 0.f;
        #pragma unroll
        for (int u = 0; u < 8; ++u) s += tl[u][t][il];
        size_t off = (size_t)t * NN + i0 + il;
        float rv = r[off];
        float wv = s + rv;                        // A = K + I
        w[off] = wv;
        float v = rv * wv;
        #pragma unroll
        for (int o = 8; o; o >>= 1) v += __shfl_down(v, o);   // reduce over 16-thread i-group
        if ((lane & 15) == 0) rwp[t * 256 + ib] = v;
    }
}

// ---------------------------------------------------------------- Chronopoulos-Gear update (+ bf16 r out)
__global__ __launch_bounds__(512) void cupd(const float* __restrict__ w, float* __restrict__ r,
                                            float* __restrict__ p, float* __restrict__ s_,
                                            float* __restrict__ x,
                                            unsigned short* __restrict__ rhi,
                                            unsigned short* __restrict__ rlo,
                                            const float* __restrict__ rrp_in,
                                            float* __restrict__ rrp_out,
                                            const float* __restrict__ rwp,
                                            const float* __restrict__ scal_in,
                                            float* __restrict__ scal_out, int first) {
    int t = blockIdx.x, c = blockIdx.y, tid = threadIdx.x;
    float rr = 0.f;
    #pragma unroll
    for (int u = 0; u < 8; ++u) rr += rrp_in[t * 8 + u];
    float rw = 0.f;
    const float* rwt = rwp + t * 256;
    #pragma unroll 8
    for (int u = 0; u < 256; ++u) rw += rwt[u];
    float alpha, beta;
    if (first) {
        beta = 0.f;
        alpha = rr / rw;
    } else {
        float ap = scal_in[t], rrprev = scal_in[TT + t];
        beta = rr / rrprev;
        alpha = rr / (rw - (beta / ap) * rr);
    }
    size_t off = (size_t)t * NN + c * 512 + tid;
    float rv = r[off], wv = w[off];
    float pn = first ? rv : fmaf(beta, p[off], rv);
    float sn = first ? wv : fmaf(beta, s_[off], wv);
    p[off] = pn; s_[off] = sn;
    x[off] += alpha * pn;
    float rn = rv - alpha * sn;
    r[off] = rn;
    unsigned short h = f2bf(rn);
    rhi[off] = h; rlo[off] = f2bf(rn - bf2f(h));
    float v = rn * rn;
    #pragma unroll
    for (int o = 32; o; o >>= 1) v += __shfl_down(v, o);
    __shared__ float red[8];
    if ((tid & 63) == 0) red[tid >> 6] = v;
    __syncthreads();
    if (tid == 0) {
        float tot = 0.f;
        #pragma unroll
        for (int u = 0; u < 8; ++u) tot += red[u];
        rrp_out[t * 8 + c] = tot;
        if (c == 0) { scal_out[t] = alpha; scal_out[TT + t] = rr; }
    }
}

// ---------------------------------------------------------------- fp32 [T][N] -> bf16 hi/lo
__global__ __launch_bounds__(512) void vec2bf(const float* __restrict__ v,
                                              unsigned short* __restrict__ hi,
                                              unsigned short* __restrict__ lo) {
    int t = blockIdx.x, c = blockIdx.y, tid = threadIdx.x;
    size_t off = (size_t)t * NN + c * 512 + tid;
    float val = v[off];
    unsigned short h = f2bf(val);
    hi[off] = h; lo[off] = f2bf(val - bf2f(h));
}

extern "C" void kernel_launch(void* const* d_in, const int* in_sizes, int n_in,
                              void* d_out, int out_size, void* d_ws, size_t ws_size,
                              hipStream_t stream) {
    const float* X = (const float*)d_in[0];   // [N, D]
    const float* y = (const float*)d_in[1];   // [N, T]
    float* out = (float*)d_out;               // [N, T]

    unsigned int* Kp = (unsigned int*)d_ws;                       // N*N uints (64 MB)
    float* w    = (float*)(Kp + (size_t)NN * NN);                 // T*N
    float* r    = w  + (size_t)TT * NN;
    float* p    = r  + (size_t)TT * NN;
    float* s_   = p  + (size_t)TT * NN;
    float* x    = s_ + (size_t)TT * NN;
    unsigned short* rhi = (unsigned short*)(x + (size_t)TT * NN); // T*N bf16
    unsigned short* rlo = rhi + (size_t)TT * NN;
    unsigned short* xhi = rlo + (size_t)TT * NN;
    unsigned short* xlo = xhi + (size_t)TT * NN;
    float* rrp  = (float*)(xlo + (size_t)TT * NN);                // 2 x 256
    float* rwp  = rrp + 512;                                      // 32 x 256
    float* scal = rwp + 32 * 256;                                 // 2 x 64
    unsigned short* Xb = (unsigned short*)(scal + 128);           // N*D bf16 (2 MB)
    float* x2v  = (float*)(Xb + (size_t)NN * DD);                 // N

    x2conv<<<NN / 4, 256, 0, stream>>>(X, x2v, Xb);
    k_build<<<dim3(NN / 128, NN / 128), 256, 0, stream>>>(Xb, x2v, Kp);
    cg_init<<<dim3(TT, 8), 512, 0, stream>>>(y, r, x, rhi, rlo, rrp);

    for (int j = 0; j < ITERS; ++j) {
        matvec_fused<0><<<NN / 16, 512, 0, stream>>>(Kp, rhi, rlo, r, w, rwp, nullptr);
        cupd<<<dim3(TT, 8), 512, 0, stream>>>(w, r, p, s_, x, rhi, rlo,
                                              rrp + (j & 1) * 256, rrp + ((j + 1) & 1) * 256,
                                              rwp,
                                              scal + (j & 1) * 64, scal + ((j + 1) & 1) * 64,
                                              j == 0 ? 1 : 0);
    }

    // predict: y_pred = K @ x (no identity term), direct transposed store
    vec2bf<<<dim3(TT, 8), 512, 0, stream>>>(x, xhi, xlo);
    matvec_fused<1><<<NN / 16, 512, 0, stream>>>(Kp, xhi, xlo, nullptr, nullptr, nullptr, out);
}

// Round 5
// 270.282 us; speedup vs baseline: 6.6684x; 1.5267x over previous
//
#include <hip/hip_runtime.h>
#include <math.h>

#define NN 4096
#define DD 256
#define TT 32
#define GAMMA (1.0f/256.0f)
#define ITERS 10
#define JBP 8            // j-chunks in matvec
#define JCH 512          // j per block
#define IB  128          // i-rows per matvec block
#define BROW (JCH + 8)   // padded LDS row (elems); 1040 B, 16B-aligned, ~2-way banks

typedef __attribute__((ext_vector_type(8))) short bf16x8;
typedef __attribute__((ext_vector_type(4))) float f32x4;

static __device__ __forceinline__ unsigned short f2bf(float f) {
    unsigned int u = __float_as_uint(f);
    unsigned int r = u + 0x7FFFu + ((u >> 16) & 1u);   // RNE
    return (unsigned short)(r >> 16);
}
static __device__ __forceinline__ float bf2f(unsigned short h) {
    return __uint_as_float((unsigned int)h << 16);
}
static __device__ __forceinline__ unsigned int pack_hilo(float v) {
    unsigned short h = f2bf(v);
    unsigned short l = f2bf(v - bf2f(h));
    return (unsigned int)h | ((unsigned int)l << 16);
}
static __device__ __forceinline__ bf16x8 mk_hi(const uint4& q0, const uint4& q1) {
    union { unsigned int u[4]; bf16x8 b; } r;
    r.u[0] = (q0.x & 0xffffu) | (q0.y << 16);
    r.u[1] = (q0.z & 0xffffu) | (q0.w << 16);
    r.u[2] = (q1.x & 0xffffu) | (q1.y << 16);
    r.u[3] = (q1.z & 0xffffu) | (q1.w << 16);
    return r.b;
}
static __device__ __forceinline__ bf16x8 mk_lo(const uint4& q0, const uint4& q1) {
    union { unsigned int u[4]; bf16x8 b; } r;
    r.u[0] = (q0.x >> 16) | (q0.y & 0xffff0000u);
    r.u[1] = (q0.z >> 16) | (q0.w & 0xffff0000u);
    r.u[2] = (q1.x >> 16) | (q1.y & 0xffff0000u);
    r.u[3] = (q1.z >> 16) | (q1.w & 0xffff0000u);
    return r.b;
}

// ---------------------------------------------------------------- x2 + bf16 convert of X
__global__ __launch_bounds__(256) void x2conv(const float* __restrict__ X,
                                              float* __restrict__ x2,
                                              unsigned short* __restrict__ Xb) {
    int wid = threadIdx.x >> 6, lane = threadIdx.x & 63;
    int row = blockIdx.x * 4 + wid;
    const float* xr = X + (size_t)row * DD;
    float4 v = *(const float4*)(xr + lane * 4);
    float s = v.x * v.x + v.y * v.y + v.z * v.z + v.w * v.w;
    #pragma unroll
    for (int o = 32; o; o >>= 1) s += __shfl_down(s, o);
    if (lane == 0) x2[row] = s;
    ushort4 h;
    h.x = f2bf(v.x); h.y = f2bf(v.y); h.z = f2bf(v.z); h.w = f2bf(v.w);
    *(ushort4*)(Xb + (size_t)row * DD + lane * 4) = h;
}

// ---------------------------------------------------------------- K = exp(-g*d2), packed bf16 hi/lo
// No LDS: Xb is 2 MB (L2-resident); fragments loaded straight from global, no barriers.
__global__ __launch_bounds__(256) void k_build(const unsigned short* __restrict__ Xb,
                                               const float* __restrict__ x2,
                                               unsigned int* __restrict__ Kp) {
    const int i0 = blockIdx.x * 128, j0 = blockIdx.y * 128;
    const int tid = threadIdx.x;
    const int wid = tid >> 6, lane = tid & 63;
    const int wr = wid >> 1, wc = wid & 1;
    const int l15 = lane & 15, l4 = lane >> 4;
    f32x4 acc[4][4] = {};
    #pragma unroll
    for (int kc = 0; kc < DD; kc += 32) {
        bf16x8 af[4], bfr[4];
        #pragma unroll
        for (int m = 0; m < 4; ++m)
            af[m] = *(const bf16x8*)(Xb + (size_t)(i0 + wr * 64 + m * 16 + l15) * DD + kc + l4 * 8);
        #pragma unroll
        for (int n = 0; n < 4; ++n)
            bfr[n] = *(const bf16x8*)(Xb + (size_t)(j0 + wc * 64 + n * 16 + l15) * DD + kc + l4 * 8);
        #pragma unroll
        for (int m = 0; m < 4; ++m)
            #pragma unroll
            for (int n = 0; n < 4; ++n)
                acc[m][n] = __builtin_amdgcn_mfma_f32_16x16x32_bf16(af[m], bfr[n], acc[m][n], 0, 0, 0);
    }
    #pragma unroll
    for (int m = 0; m < 4; ++m) {
        #pragma unroll
        for (int rg = 0; rg < 4; ++rg) {
            int i = i0 + wr * 64 + m * 16 + l4 * 4 + rg;
            float x2i = x2[i];
            #pragma unroll
            for (int n = 0; n < 4; ++n) {
                int j = j0 + wc * 64 + n * 16 + l15;
                float d2 = fmaxf(x2i + x2[j] - 2.f * acc[m][n][rg], 0.f);
                Kp[(size_t)i * NN + j] = pack_hilo(__expf(-GAMMA * d2));
            }
        }
    }
}

// ---------------------------------------------------------------- CG init: r = y^T (fp32 + bf16 hi/lo), x = 0
__global__ __launch_bounds__(512) void cg_init(const float* __restrict__ y,
                                               float* __restrict__ r, float* __restrict__ x,
                                               unsigned short* __restrict__ rhi,
                                               unsigned short* __restrict__ rlo,
                                               float* __restrict__ rrp) {
    int t = blockIdx.x, c = blockIdx.y, tid = threadIdx.x;
    int i = c * 512 + tid;
    float v = y[(size_t)i * TT + t];
    size_t off = (size_t)t * NN + i;
    r[off] = v; x[off] = 0.f;
    unsigned short h = f2bf(v);
    rhi[off] = h; rlo[off] = f2bf(v - bf2f(h));
    float s = v * v;
    #pragma unroll
    for (int o = 32; o; o >>= 1) s += __shfl_down(s, o);
    __shared__ float red[8];
    if ((tid & 63) == 0) red[tid >> 6] = s;
    __syncthreads();
    if (tid == 0) {
        float tot = 0.f;
        #pragma unroll
        for (int u = 0; u < 8; ++u) tot += red[u];
        rrp[t * 8 + c] = tot;
    }
}

// ---------------------------------------------------------------- matvec: part[jb][t][i] = sum_{j in jb} K[i][j]*v[t][j]
// Block = 128 i-rows (8 waves x 16) x 512 j. B staged once into LDS (shared by all waves).
__global__ __launch_bounds__(512) void matvec_part(const unsigned int* __restrict__ Kp,
                                                   const unsigned short* __restrict__ vhi,
                                                   const unsigned short* __restrict__ vlo,
                                                   float* __restrict__ part) {
    __shared__ __align__(16) unsigned int smem[(2 * 32 * BROW * 2) / 4];  // 66560 B
    unsigned short* Bh = (unsigned short*)smem;
    unsigned short* Bl = Bh + 32 * BROW;
    float* tl = (float*)smem;                     // reused after compute: [8][32][17]
    const int ib = blockIdx.x;                    // 32
    const int jb = blockIdx.y;                    // 8
    const int tid = threadIdx.x;
    const int wid = tid >> 6, lane = tid & 63;
    const int l15 = lane & 15, l4 = lane >> 4;
    // stage B: 32 t-rows x 512 j, hi and lo
    #pragma unroll
    for (int s = 0; s < 4; ++s) {
        int c = s * 512 + tid;                    // 2048 chunks of 8 elems
        int row = c >> 6, col8 = c & 63;
        uint4 h = *(const uint4*)(vhi + (size_t)row * NN + jb * JCH + col8 * 8);
        *(uint4*)(Bh + row * BROW + col8 * 8) = h;
        uint4 l = *(const uint4*)(vlo + (size_t)row * NN + jb * JCH + col8 * 8);
        *(uint4*)(Bl + row * BROW + col8 * 8) = l;
    }
    __syncthreads();
    const unsigned int* Ap = Kp + (size_t)(ib * IB + wid * 16 + l15) * NN + jb * JCH + l4 * 8;
    const unsigned short* bhp = Bh + l15 * BROW + l4 * 8;
    const unsigned short* blp = Bl + l15 * BROW + l4 * 8;
    f32x4 acc0 = {}, acc1 = {};
    #pragma unroll 4
    for (int jc = 0; jc < JCH; jc += 32) {
        uint4 q0 = *(const uint4*)(Ap + jc);
        uint4 q1 = *(const uint4*)(Ap + jc + 4);
        bf16x8 ah = mk_hi(q0, q1);
        bf16x8 al = mk_lo(q0, q1);
        bf16x8 bh0 = *(const bf16x8*)(bhp + jc);
        bf16x8 bh1 = *(const bf16x8*)(bhp + 16 * BROW + jc);
        bf16x8 bl0 = *(const bf16x8*)(blp + jc);
        bf16x8 bl1 = *(const bf16x8*)(blp + 16 * BROW + jc);
        acc0 = __builtin_amdgcn_mfma_f32_16x16x32_bf16(ah, bh0, acc0, 0, 0, 0);
        acc1 = __builtin_amdgcn_mfma_f32_16x16x32_bf16(ah, bh1, acc1, 0, 0, 0);
        acc0 = __builtin_amdgcn_mfma_f32_16x16x32_bf16(al, bh0, acc0, 0, 0, 0);
        acc1 = __builtin_amdgcn_mfma_f32_16x16x32_bf16(al, bh1, acc1, 0, 0, 0);
        acc0 = __builtin_amdgcn_mfma_f32_16x16x32_bf16(ah, bl0, acc0, 0, 0, 0);
        acc1 = __builtin_amdgcn_mfma_f32_16x16x32_bf16(ah, bl1, acc1, 0, 0, 0);
    }
    __syncthreads();                               // all waves done reading B -> reuse as tl
    // C layout: row (i-local) = l4*4+rg, col (t) = l15. Transpose via LDS, wave-local tile.
    #pragma unroll
    for (int rg = 0; rg < 4; ++rg) {
        tl[(wid * 32 + l15) * 17 + l4 * 4 + rg]      = acc0[rg];
        tl[(wid * 32 + 16 + l15) * 17 + l4 * 4 + rg] = acc1[rg];
    }
    __syncthreads();
    #pragma unroll
    for (int q = 0; q < 8; ++q) {
        int idx = q * 64 + lane;                   // t = idx>>4, il = idx&15
        int t = idx >> 4, il = idx & 15;
        part[((size_t)jb * TT + t) * NN + ib * IB + wid * 16 + il] = tl[(wid * 32 + t) * 17 + il];
    }
}

// ---------------------------------------------------------------- w = sum_b part + r ; rw partials
__global__ __launch_bounds__(512) void bred(const float* __restrict__ part, const float* __restrict__ r,
                                            float* __restrict__ w, float* __restrict__ rwp) {
    int t = blockIdx.x, c = blockIdx.y, tid = threadIdx.x;
    int i = c * 512 + tid;
    float s = 0.f;
    #pragma unroll
    for (int b = 0; b < JBP; ++b) s += part[((size_t)b * TT + t) * NN + i];
    float rv = r[(size_t)t * NN + i];
    s += rv;                                   // A = K + I
    w[(size_t)t * NN + i] = s;
    float v = rv * s;
    #pragma unroll
    for (int o = 32; o; o >>= 1) v += __shfl_down(v, o);
    __shared__ float red[8];
    if ((tid & 63) == 0) red[tid >> 6] = v;
    __syncthreads();
    if (tid == 0) {
        float tot = 0.f;
        #pragma unroll
        for (int u = 0; u < 8; ++u) tot += red[u];
        rwp[t * 8 + c] = tot;
    }
}

// ---------------------------------------------------------------- Chronopoulos-Gear update (+ bf16 r out)
__global__ __launch_bounds__(512) void cupd(const float* __restrict__ w, float* __restrict__ r,
                                            float* __restrict__ p, float* __restrict__ s_,
                                            float* __restrict__ x,
                                            unsigned short* __restrict__ rhi,
                                            unsigned short* __restrict__ rlo,
                                            const float* __restrict__ rrp_in,
                                            float* __restrict__ rrp_out,
                                            const float* __restrict__ rwp,
                                            const float* __restrict__ scal_in,
                                            float* __restrict__ scal_out, int first) {
    int t = blockIdx.x, c = blockIdx.y, tid = threadIdx.x;
    float rr = 0.f, rw = 0.f;
    #pragma unroll
    for (int u = 0; u < 8; ++u) { rr += rrp_in[t * 8 + u]; rw += rwp[t * 8 + u]; }
    float alpha, beta;
    if (first) {
        beta = 0.f;
        alpha = rr / rw;
    } else {
        float ap = scal_in[t], rrprev = scal_in[TT + t];
        beta = rr / rrprev;
        alpha = rr / (rw - (beta / ap) * rr);
    }
    size_t off = (size_t)t * NN + c * 512 + tid;
    float rv = r[off], wv = w[off];
    float pn = first ? rv : fmaf(beta, p[off], rv);
    float sn = first ? wv : fmaf(beta, s_[off], wv);
    p[off] = pn; s_[off] = sn;
    x[off] += alpha * pn;
    float rn = rv - alpha * sn;
    r[off] = rn;
    unsigned short h = f2bf(rn);
    rhi[off] = h; rlo[off] = f2bf(rn - bf2f(h));
    float v = rn * rn;
    #pragma unroll
    for (int o = 32; o; o >>= 1) v += __shfl_down(v, o);
    __shared__ float red[8];
    if ((tid & 63) == 0) red[tid >> 6] = v;
    __syncthreads();
    if (tid == 0) {
        float tot = 0.f;
        #pragma unroll
        for (int u = 0; u < 8; ++u) tot += red[u];
        rrp_out[t * 8 + c] = tot;
        if (c == 0) { scal_out[t] = alpha; scal_out[TT + t] = rr; }
    }
}

// ---------------------------------------------------------------- fp32 [T][N] -> bf16 hi/lo
__global__ __launch_bounds__(512) void vec2bf(const float* __restrict__ v,
                                              unsigned short* __restrict__ hi,
                                              unsigned short* __restrict__ lo) {
    int t = blockIdx.x, c = blockIdx.y, tid = threadIdx.x;
    size_t off = (size_t)t * NN + c * 512 + tid;
    float val = v[off];
    unsigned short h = f2bf(val);
    hi[off] = h; lo[off] = f2bf(val - bf2f(h));
}

// ---------------------------------------------------------------- y_pred[i][t] = sum_b part (transposed write)
__global__ __launch_bounds__(256) void predict_out(const float* __restrict__ part,
                                                   float* __restrict__ out) {
    __shared__ float st[TT][65];
    const int i0 = blockIdx.x * 64;
    const int tid = threadIdx.x;
    #pragma unroll
    for (int ph = 0; ph < 8; ++ph) {
        int idx = ph * 256 + tid;
        int il = idx & 63, t = idx >> 6;
        float s = 0.f;
        #pragma unroll
        for (int b = 0; b < JBP; ++b) s += part[((size_t)b * TT + t) * NN + i0 + il];
        st[t][il] = s;
    }
    __syncthreads();
    #pragma unroll
    for (int ph = 0; ph < 8; ++ph) {
        int idx = ph * 256 + tid;
        int t = idx & 31, il = idx >> 5;
        out[(size_t)(i0 + il) * TT + t] = st[t][il];
    }
}

extern "C" void kernel_launch(void* const* d_in, const int* in_sizes, int n_in,
                              void* d_out, int out_size, void* d_ws, size_t ws_size,
                              hipStream_t stream) {
    const float* X = (const float*)d_in[0];   // [N, D]
    const float* y = (const float*)d_in[1];   // [N, T]
    float* out = (float*)d_out;               // [N, T]

    unsigned int* Kp = (unsigned int*)d_ws;                       // N*N uints (64 MB)
    float* part = (float*)(Kp + (size_t)NN * NN);                 // JBP*T*N (4 MB)
    float* w    = part + (size_t)JBP * TT * NN;                   // T*N
    float* r    = w  + (size_t)TT * NN;
    float* p    = r  + (size_t)TT * NN;
    float* s_   = p  + (size_t)TT * NN;
    float* x    = s_ + (size_t)TT * NN;
    unsigned short* rhi = (unsigned short*)(x + (size_t)TT * NN); // T*N bf16
    unsigned short* rlo = rhi + (size_t)TT * NN;
    unsigned short* xhi = rlo + (size_t)TT * NN;
    unsigned short* xlo = xhi + (size_t)TT * NN;
    float* rrp  = (float*)(xlo + (size_t)TT * NN);                // 2 x 256
    float* rwp  = rrp + 512;                                      // 256
    float* scal = rwp + 256;                                      // 2 x 64
    unsigned short* Xb = (unsigned short*)(scal + 128);           // N*D bf16 (2 MB)
    float* x2v  = (float*)(Xb + (size_t)NN * DD);                 // N

    x2conv<<<NN / 4, 256, 0, stream>>>(X, x2v, Xb);
    k_build<<<dim3(NN / 128, NN / 128), 256, 0, stream>>>(Xb, x2v, Kp);
    cg_init<<<dim3(TT, 8), 512, 0, stream>>>(y, r, x, rhi, rlo, rrp);

    for (int j = 0; j < ITERS; ++j) {
        matvec_part<<<dim3(NN / IB, JBP), 512, 0, stream>>>(Kp, rhi, rlo, part);
        bred<<<dim3(TT, 8), 512, 0, stream>>>(part, r, w, rwp);
        cupd<<<dim3(TT, 8), 512, 0, stream>>>(w, r, p, s_, x, rhi, rlo,
                                              rrp + (j & 1) * 256, rrp + ((j + 1) & 1) * 256,
                                              rwp,
                                              scal + (j & 1) * 64, scal + ((j + 1) & 1) * 64,
                                              j == 0 ? 1 : 0);
    }

    // predict: y_pred = K @ x (no identity term)
    vec2bf<<<dim3(TT, 8), 512, 0, stream>>>(x, xhi, xlo);
    matvec_part<<<dim3(NN / IB, JBP), 512, 0, stream>>>(Kp, xhi, xlo, part);
    predict_out<<<NN / 64, 256, 0, stream>>>(part, out);
}

// Round 6
// 253.937 us; speedup vs baseline: 7.0976x; 1.0644x over previous
//
#include <hip/hip_runtime.h>
#include <math.h>

#define NN 4096
#define DD 256
#define TT 32
#define GAMMA (1.0f/256.0f)
#define ITERS 10
#define JBP 8            // j-chunks in matvec
#define JCH 512          // j per matvec block
#define IB  128          // i-rows per matvec block
#define BROW (JCH + 8)   // padded LDS row (elems): 1040 B -> 2-way banks (free)
#define KB_PAD 40        // bf16 elems per LDS row in k_build staging

typedef __attribute__((ext_vector_type(8))) short bf16x8;
typedef __attribute__((ext_vector_type(4))) float f32x4;

static __device__ __forceinline__ unsigned short f2bf(float f) {
    unsigned int u = __float_as_uint(f);
    unsigned int r = u + 0x7FFFu + ((u >> 16) & 1u);   // RNE
    return (unsigned short)(r >> 16);
}
static __device__ __forceinline__ float bf2f(unsigned short h) {
    return __uint_as_float((unsigned int)h << 16);
}

// ---------------------------------------------------------------- x2 + bf16 convert of X
__global__ __launch_bounds__(256) void x2conv(const float* __restrict__ X,
                                              float* __restrict__ x2,
                                              unsigned short* __restrict__ Xb) {
    int wid = threadIdx.x >> 6, lane = threadIdx.x & 63;
    int row = blockIdx.x * 4 + wid;
    const float* xr = X + (size_t)row * DD;
    float4 v = *(const float4*)(xr + lane * 4);
    float s = v.x * v.x + v.y * v.y + v.z * v.z + v.w * v.w;
    #pragma unroll
    for (int o = 32; o; o >>= 1) s += __shfl_down(s, o);
    if (lane == 0) x2[row] = s;
    ushort4 h;
    h.x = f2bf(v.x); h.y = f2bf(v.y); h.z = f2bf(v.z); h.w = f2bf(v.w);
    *(ushort4*)(Xb + (size_t)row * DD + lane * 4) = h;
}

// ---------------------------------------------------------------- K = exp(-g*d2), bf16 out
// 128(i) x 256(j) tile, LDS-staged, 4 waves each 64x128 (4x8 MFMA frags).
__global__ __launch_bounds__(256) void k_build(const unsigned short* __restrict__ Xb,
                                               const float* __restrict__ x2,
                                               unsigned short* __restrict__ Ku) {
    __shared__ unsigned short As[128 * KB_PAD];   // 10240 B
    __shared__ unsigned short Bs[256 * KB_PAD];   // 20480 B
    const int i0 = blockIdx.x * 128, j0 = blockIdx.y * 256;
    const int tid = threadIdx.x;
    const int wid = tid >> 6, lane = tid & 63;
    const int wr = wid >> 1, wc = wid & 1;
    const int l15 = lane & 15, l4 = lane >> 4;
    f32x4 acc[4][8] = {};
    for (int kc = 0; kc < DD; kc += 32) {
        __syncthreads();
        #pragma unroll
        for (int s = 0; s < 2; ++s) {             // A: 128 rows x 4 chunks of 8
            int idx = s * 256 + tid;
            int row = idx >> 2, c = idx & 3;
            uint4 d = *(const uint4*)(Xb + (size_t)(i0 + row) * DD + kc + c * 8);
            *(uint4*)(As + row * KB_PAD + c * 8) = d;
        }
        #pragma unroll
        for (int s = 0; s < 4; ++s) {             // B: 256 rows x 4 chunks of 8
            int idx = s * 256 + tid;
            int row = idx >> 2, c = idx & 3;
            uint4 d = *(const uint4*)(Xb + (size_t)(j0 + row) * DD + kc + c * 8);
            *(uint4*)(Bs + row * KB_PAD + c * 8) = d;
        }
        __syncthreads();
        bf16x8 af[4], bfr[8];
        #pragma unroll
        for (int m = 0; m < 4; ++m)
            af[m] = *(const bf16x8*)(As + (wr * 64 + m * 16 + l15) * KB_PAD + l4 * 8);
        #pragma unroll
        for (int n = 0; n < 8; ++n)
            bfr[n] = *(const bf16x8*)(Bs + (wc * 128 + n * 16 + l15) * KB_PAD + l4 * 8);
        #pragma unroll
        for (int m = 0; m < 4; ++m)
            #pragma unroll
            for (int n = 0; n < 8; ++n)
                acc[m][n] = __builtin_amdgcn_mfma_f32_16x16x32_bf16(af[m], bfr[n], acc[m][n], 0, 0, 0);
    }
    #pragma unroll
    for (int m = 0; m < 4; ++m) {
        #pragma unroll
        for (int rg = 0; rg < 4; ++rg) {
            int i = i0 + wr * 64 + m * 16 + l4 * 4 + rg;
            float x2i = x2[i];
            #pragma unroll
            for (int n = 0; n < 8; ++n) {
                int j = j0 + wc * 128 + n * 16 + l15;
                float d2 = fmaxf(x2i + x2[j] - 2.f * acc[m][n][rg], 0.f);
                Ku[(size_t)i * NN + j] = f2bf(__expf(-GAMMA * d2));
            }
        }
    }
}

// ---------------------------------------------------------------- CG init: r = y^T (fp32 + bf16 hi/lo), x = 0
__global__ __launch_bounds__(512) void cg_init(const float* __restrict__ y,
                                               float* __restrict__ r, float* __restrict__ x,
                                               unsigned short* __restrict__ rhi,
                                               unsigned short* __restrict__ rlo,
                                               float* __restrict__ rrp) {
    int t = blockIdx.x, c = blockIdx.y, tid = threadIdx.x;
    int i = c * 512 + tid;
    float v = y[(size_t)i * TT + t];
    size_t off = (size_t)t * NN + i;
    r[off] = v; x[off] = 0.f;
    unsigned short h = f2bf(v);
    rhi[off] = h; rlo[off] = f2bf(v - bf2f(h));
    float s = v * v;
    #pragma unroll
    for (int o = 32; o; o >>= 1) s += __shfl_down(s, o);
    __shared__ float red[8];
    if ((tid & 63) == 0) red[tid >> 6] = s;
    __syncthreads();
    if (tid == 0) {
        float tot = 0.f;
        #pragma unroll
        for (int u = 0; u < 8; ++u) tot += red[u];
        rrp[t * 8 + c] = tot;
    }
}

// ---------------------------------------------------------------- matvec: part[jb][t][i] = sum_{j in jb} K[i][j]*v[t][j]
// Block = 128 i-rows (8 waves x 16) x 512 j. v (hi/lo) staged in LDS.
// RED=1: also emit rKvp[t][blk] = sum_{i in blk} r[t][i] * (Kv)[t][i]
template<int RED>
__global__ __launch_bounds__(512) void matvec_part(const unsigned short* __restrict__ Ku,
                                                   const unsigned short* __restrict__ vhi,
                                                   const unsigned short* __restrict__ vlo,
                                                   const float* __restrict__ r,
                                                   float* __restrict__ part,
                                                   float* __restrict__ rKvp) {
    __shared__ __align__(16) unsigned short Bh[32 * BROW];   // 33280 B
    __shared__ __align__(16) unsigned short Bl[32 * BROW];   // 33280 B
    __shared__ float redb[8][33];
    const int ib = blockIdx.x;                    // 32
    const int jb = blockIdx.y;                    // 8
    const int bid = jb * 32 + ib;                 // 0..255
    const int tid = threadIdx.x;
    const int wid = tid >> 6, lane = tid & 63;
    const int l15 = lane & 15, l4 = lane >> 4;
    // stage v: 32 t-rows x 512 j, hi and lo
    #pragma unroll
    for (int s = 0; s < 4; ++s) {
        int c = s * 512 + tid;                    // 2048 chunks of 8 elems
        int row = c >> 6, col8 = c & 63;
        uint4 h = *(const uint4*)(vhi + (size_t)row * NN + jb * JCH + col8 * 8);
        *(uint4*)(Bh + row * BROW + col8 * 8) = h;
        uint4 l = *(const uint4*)(vlo + (size_t)row * NN + jb * JCH + col8 * 8);
        *(uint4*)(Bl + row * BROW + col8 * 8) = l;
    }
    __syncthreads();
    const unsigned short* Ap = Ku + (size_t)(ib * IB + wid * 16 + l15) * NN + jb * JCH + l4 * 8;
    const unsigned short* bhp = Bh + l15 * BROW + l4 * 8;
    const unsigned short* blp = Bl + l15 * BROW + l4 * 8;
    f32x4 acc0 = {}, acc1 = {};
    #pragma unroll 4
    for (int jc = 0; jc < JCH; jc += 32) {
        bf16x8 a = *(const bf16x8*)(Ap + jc);
        bf16x8 bh0 = *(const bf16x8*)(bhp + jc);
        bf16x8 bh1 = *(const bf16x8*)(bhp + 16 * BROW + jc);
        bf16x8 bl0 = *(const bf16x8*)(blp + jc);
        bf16x8 bl1 = *(const bf16x8*)(blp + 16 * BROW + jc);
        acc0 = __builtin_amdgcn_mfma_f32_16x16x32_bf16(a, bh0, acc0, 0, 0, 0);
        acc1 = __builtin_amdgcn_mfma_f32_16x16x32_bf16(a, bh1, acc1, 0, 0, 0);
        acc0 = __builtin_amdgcn_mfma_f32_16x16x32_bf16(a, bl0, acc0, 0, 0, 0);
        acc1 = __builtin_amdgcn_mfma_f32_16x16x32_bf16(a, bl1, acc1, 0, 0, 0);
    }
    __syncthreads();                               // done reading Bh/Bl -> reuse as tl
    float* tl = (float*)Bh;                        // [8][32][17] floats = 17408 B
    #pragma unroll
    for (int rg = 0; rg < 4; ++rg) {
        tl[(wid * 32 + l15) * 17 + l4 * 4 + rg]      = acc0[rg];
        tl[(wid * 32 + 16 + l15) * 17 + l4 * 4 + rg] = acc1[rg];
    }
    __syncthreads();
    #pragma unroll
    for (int q = 0; q < 8; ++q) {
        int idx = q * 64 + lane;
        int t = idx >> 4, il = idx & 15;
        int gi = ib * IB + wid * 16 + il;
        float val = tl[(wid * 32 + t) * 17 + il];
        part[((size_t)jb * TT + t) * NN + gi] = val;
        if (RED) {
            float cq = r[(size_t)t * NN + gi] * val;
            #pragma unroll
            for (int o = 8; o; o >>= 1) cq += __shfl_down(cq, o);
            if (il == 0) redb[wid][t] = cq;
        }
    }
    if (RED) {
        __syncthreads();
        if (tid < 32) {
            float s = 0.f;
            #pragma unroll
            for (int u = 0; u < 8; ++u) s += redb[u][tid];
            rKvp[tid * 256 + bid] = s;
        }
    }
}

// ---------------------------------------------------------------- Chronopoulos-Gear update (absorbs bred)
// w = sum_b part + r computed in-register; rw = sum(rKvp) + rr.
__global__ __launch_bounds__(512) void cupd(const float* __restrict__ part, float* __restrict__ r,
                                            float* __restrict__ p, float* __restrict__ s_,
                                            float* __restrict__ x,
                                            unsigned short* __restrict__ rhi,
                                            unsigned short* __restrict__ rlo,
                                            const float* __restrict__ rrp_in,
                                            float* __restrict__ rrp_out,
                                            const float* __restrict__ rKvp,
                                            const float* __restrict__ scal_in,
                                            float* __restrict__ scal_out, int first) {
    int t = blockIdx.x, c = blockIdx.y, tid = threadIdx.x;
    float rr = 0.f;
    #pragma unroll
    for (int u = 0; u < 8; ++u) rr += rrp_in[t * 8 + u];
    float rw = rr;                                 // r.w = r.Kv + r.r
    const float* rk = rKvp + t * 256;
    #pragma unroll 8
    for (int u = 0; u < 256; ++u) rw += rk[u];
    float alpha, beta;
    if (first) {
        beta = 0.f;
        alpha = rr / rw;
    } else {
        float ap = scal_in[t], rrprev = scal_in[TT + t];
        beta = rr / rrprev;
        alpha = rr / (rw - (beta / ap) * rr);
    }
    int i = c * 512 + tid;
    size_t off = (size_t)t * NN + i;
    float s = 0.f;
    #pragma unroll
    for (int b = 0; b < JBP; ++b) s += part[((size_t)b * TT + t) * NN + i];
    float rv = r[off];
    float wv = s + rv;                             // A = K + I
    float pn = first ? rv : fmaf(beta, p[off], rv);
    float sn = first ? wv : fmaf(beta, s_[off], wv);
    p[off] = pn; s_[off] = sn;
    x[off] += alpha * pn;
    float rn = rv - alpha * sn;
    r[off] = rn;
    unsigned short h = f2bf(rn);
    rhi[off] = h; rlo[off] = f2bf(rn - bf2f(h));
    float v = rn * rn;
    #pragma unroll
    for (int o = 32; o; o >>= 1) v += __shfl_down(v, o);
    __shared__ float red[8];
    if ((tid & 63) == 0) red[tid >> 6] = v;
    __syncthreads();
    if (tid == 0) {
        float tot = 0.f;
        #pragma unroll
        for (int u = 0; u < 8; ++u) tot += red[u];
        rrp_out[t * 8 + c] = tot;
        if (c == 0) { scal_out[t] = alpha; scal_out[TT + t] = rr; }
    }
}

// ---------------------------------------------------------------- fp32 [T][N] -> bf16 hi/lo
__global__ __launch_bounds__(512) void vec2bf(const float* __restrict__ v,
                                              unsigned short* __restrict__ hi,
                                              unsigned short* __restrict__ lo) {
    int t = blockIdx.x, c = blockIdx.y, tid = threadIdx.x;
    size_t off = (size_t)t * NN + c * 512 + tid;
    float val = v[off];
    unsigned short h = f2bf(val);
    hi[off] = h; lo[off] = f2bf(val - bf2f(h));
}

// ---------------------------------------------------------------- y_pred[i][t] = sum_b part (transposed write)
__global__ __launch_bounds__(256) void predict_out(const float* __restrict__ part,
                                                   float* __restrict__ out) {
    __shared__ float st[TT][65];
    const int i0 = blockIdx.x * 64;
    const int tid = threadIdx.x;
    #pragma unroll
    for (int ph = 0; ph < 8; ++ph) {
        int idx = ph * 256 + tid;
        int il = idx & 63, t = idx >> 6;
        float s = 0.f;
        #pragma unroll
        for (int b = 0; b < JBP; ++b) s += part[((size_t)b * TT + t) * NN + i0 + il];
        st[t][il] = s;
    }
    __syncthreads();
    #pragma unroll
    for (int ph = 0; ph < 8; ++ph) {
        int idx = ph * 256 + tid;
        int t = idx & 31, il = idx >> 5;
        out[(size_t)(i0 + il) * TT + t] = st[t][il];
    }
}

extern "C" void kernel_launch(void* const* d_in, const int* in_sizes, int n_in,
                              void* d_out, int out_size, void* d_ws, size_t ws_size,
                              hipStream_t stream) {
    const float* X = (const float*)d_in[0];   // [N, D]
    const float* y = (const float*)d_in[1];   // [N, T]
    float* out = (float*)d_out;               // [N, T]

    unsigned short* Ku = (unsigned short*)d_ws;                   // N*N bf16 (32 MB)
    float* part = (float*)(Ku + (size_t)NN * NN);                 // JBP*T*N (4 MB)
    float* r    = part + (size_t)JBP * TT * NN;                   // T*N
    float* p    = r  + (size_t)TT * NN;
    float* s_   = p  + (size_t)TT * NN;
    float* x    = s_ + (size_t)TT * NN;
    unsigned short* rhi = (unsigned short*)(x + (size_t)TT * NN); // T*N bf16
    unsigned short* rlo = rhi + (size_t)TT * NN;
    unsigned short* xhi = rlo + (size_t)TT * NN;
    unsigned short* xlo = xhi + (size_t)TT * NN;
    float* rrp  = (float*)(xlo + (size_t)TT * NN);                // 2 x 256
    float* rKvp = rrp + 512;                                      // 32 x 256
    float* scal = rKvp + 32 * 256;                                // 2 x 64
    unsigned short* Xb = (unsigned short*)(scal + 128);           // N*D bf16 (2 MB)
    float* x2v  = (float*)(Xb + (size_t)NN * DD);                 // N

    x2conv<<<NN / 4, 256, 0, stream>>>(X, x2v, Xb);
    k_build<<<dim3(NN / 128, NN / 256), 256, 0, stream>>>(Xb, x2v, Ku);
    cg_init<<<dim3(TT, 8), 512, 0, stream>>>(y, r, x, rhi, rlo, rrp);

    for (int j = 0; j < ITERS; ++j) {
        matvec_part<1><<<dim3(NN / IB, JBP), 512, 0, stream>>>(Ku, rhi, rlo, r, part, rKvp);
        cupd<<<dim3(TT, 8), 512, 0, stream>>>(part, r, p, s_, x, rhi, rlo,
                                              rrp + (j & 1) * 256, rrp + ((j + 1) & 1) * 256,
                                              rKvp,
                                              scal + (j & 1) * 64, scal + ((j + 1) & 1) * 64,
                                              j == 0 ? 1 : 0);
    }

    // predict: y_pred = K @ x (no identity term)
    vec2bf<<<dim3(TT, 8), 512, 0, stream>>>(x, xhi, xlo);
    matvec_part<0><<<dim3(NN / IB, JBP), 512, 0, stream>>>(Ku, xhi, xlo, nullptr, part, nullptr);
    predict_out<<<NN / 64, 256, 0, stream>>>(part, out);
}